// Round 1
// baseline (717.130 us; speedup 1.0000x reference)
//
#include <hip/hip_runtime.h>

#define CIN 128
#define COUT 256
#define IH 96
#define IW 96
#define NB 8
#define HW (IH*IW)          // 9216
#define NPIX (NB*HW)        // 73728
#define BST 136             // padded k-stride (bf16 elems) for B tiles

typedef __attribute__((ext_vector_type(8))) short short8;
typedef __attribute__((ext_vector_type(4))) float floatx4;
typedef __attribute__((ext_vector_type(4))) unsigned int uintx4;

static __device__ __forceinline__ short f2bf(float f) {
  unsigned int u = __builtin_bit_cast(unsigned int, f);
  u = u + 0x7fffu + ((u >> 16) & 1u);
  return (short)(u >> 16);
}

// ---------------------------------------------------------------------------
// Kernel 0: repack conv weights to bf16, [tap][row n][k=c] with k-stride BST.
//   Bt2: main weights,   9 x 256 x 136   (row o,  k = c)
//   Bt1: offset|mask w,  9 x  32 x 136   (row ch: 0..17 offset, 18..26 mask)
// ---------------------------------------------------------------------------
__global__ void prep_weights(const float* __restrict__ weight,
                             const float* __restrict__ offset_w,
                             const float* __restrict__ mask_w,
                             short* __restrict__ Bt2,
                             short* __restrict__ Bt1) {
  int idx = blockIdx.x * 256 + threadIdx.x;
  const int n2 = 9 * COUT * BST;
  if (idx < n2) {
    int c = idx % BST;
    int t = idx / BST;
    int o = t % COUT, tap = t / COUT;
    float v = (c < CIN) ? weight[(o * CIN + c) * 9 + tap] : 0.f;
    Bt2[idx] = f2bf(v);
  } else {
    int j = idx - n2;
    const int n1 = 9 * 32 * BST;
    if (j < n1) {
      int c = j % BST;
      int t = j / BST;
      int n = t % 32, tap = t / 32;
      float v = 0.f;
      if (c < CIN && n < 27)
        v = (n < 18) ? offset_w[(n * CIN + c) * 9 + tap]
                     : mask_w[((n - 18) * CIN + c) * 9 + tap];
      Bt1[j] = f2bf(v);
    }
  }
}

// ---------------------------------------------------------------------------
// Kernel 1: offset+mask conv via MFMA.  Block: 64 pixels x N=32, K=1152.
// Waves split M: wave wv owns pixels [p0+16*wv, +16).  A-frag gathered
// directly from x (im2col, zero border).  Out: pm[pixel][32] fp32
// (ch 0..17 = offsets, 18..26 = sigmoid(mask)).
// ---------------------------------------------------------------------------
__global__ __launch_bounds__(256, 4)
void offmask_kernel(const float* __restrict__ x,
                    const short* __restrict__ Bt1,
                    const float* __restrict__ offset_b,
                    const float* __restrict__ mask_b,
                    float* __restrict__ pm) {
  __shared__ short blds[32 * BST];          // 8704 B

  const int tid  = threadIdx.x;
  const int lane = tid & 63;
  const int wv   = tid >> 6;
  const int q    = lane >> 4;
  const int m    = lane & 15;
  const int p0   = blockIdx.x * 64;
  const int b    = p0 / HW;
  const int p    = p0 + wv * 16 + m;        // this lane's A-row pixel
  const int hw   = p % HW;
  const int h    = hw / IW, w_ = hw % IW;
  const float* xb = x + (size_t)b * CIN * HW;

  floatx4 acc[2];
  acc[0] = (floatx4){0.f, 0.f, 0.f, 0.f};
  acc[1] = (floatx4){0.f, 0.f, 0.f, 0.f};

  for (int tap = 0; tap < 9; ++tap) {
    __syncthreads();
    {
      const uintx4* src = (const uintx4*)(Bt1 + tap * 32 * BST);
      uintx4* dst = (uintx4*)blds;
      for (int i = tid; i < 32 * BST * 2 / 16; i += 256) dst[i] = src[i];
    }
    __syncthreads();

    const int kh = tap / 3, kw = tap % 3;
    const int iy = h + kh - 1, ix = w_ + kw - 1;
    const bool vald = (iy >= 0 && iy < IH && ix >= 0 && ix < IW);
    const float* xpt = xb + iy * IW + ix;   // only deref'd when vald

    #pragma unroll
    for (int kq = 0; kq < 4; ++kq) {
      const int cbase = kq * 32 + q * 8;
      short8 a;
      #pragma unroll
      for (int j = 0; j < 8; ++j) {
        float v = vald ? xpt[(cbase + j) * HW] : 0.f;
        a[j] = f2bf(v);
      }
      #pragma unroll
      for (int ni = 0; ni < 2; ++ni) {
        const short8* bf = (const short8*)(blds + (ni * 16 + m) * BST + cbase);
        acc[ni] = __builtin_amdgcn_mfma_f32_16x16x32_bf16(a, *bf, acc[ni], 0, 0, 0);
      }
    }
  }

  // Epilogue: D row=(q*4+r) -> pixel, col=m -> channel.
  #pragma unroll
  for (int ni = 0; ni < 2; ++ni) {
    int ch = ni * 16 + m;
    if (ch < 27) {
      float cb = (ch < 18) ? offset_b[ch] : mask_b[ch - 18];
      #pragma unroll
      for (int r = 0; r < 4; ++r) {
        int pp = p0 + wv * 16 + q * 4 + r;
        float v = acc[ni][r] + cb;
        if (ch >= 18) v = 1.f / (1.f + expf(-v));
        pm[(size_t)pp * 32 + ch] = v;
      }
    }
  }
}

// ---------------------------------------------------------------------------
// Kernel 2: fused bilinear sampling + deformable GEMM.
// Block: 64 pixels x N=256, K = 9 taps x 128 ch.  Waves split M.
// A-frags: bilinear samples (x mask, x validity) gathered to registers.
// B: Bt2 staged to LDS per (tap, 128-row half).  Epilogue via LDS transpose.
// ---------------------------------------------------------------------------
__global__ __launch_bounds__(256, 3)
void deform_main(const float* __restrict__ x,
                 const short* __restrict__ Bt2,
                 const float* __restrict__ pm,
                 const float* __restrict__ bias,
                 float* __restrict__ out) {
  __shared__ short blds[128 * BST];         // 34816 B
  float* elds = (float*)blds;               // epilogue reuse: 128*65*4 = 33280 B

  const int tid  = threadIdx.x;
  const int lane = tid & 63;
  const int wv   = tid >> 6;
  const int q    = lane >> 4;
  const int m    = lane & 15;
  const int p0   = blockIdx.x * 64;
  const int b    = p0 / HW;
  const int p    = p0 + wv * 16 + m;        // this lane's A-row pixel
  const int hw   = p % HW;
  const int h    = hw / IW, w_ = hw % IW;
  const float* xb  = x + (size_t)b * CIN * HW;
  const float* pmp = pm + (size_t)p * 32;

  floatx4 acc[16];
  #pragma unroll
  for (int i = 0; i < 16; ++i) acc[i] = (floatx4){0.f, 0.f, 0.f, 0.f};

  for (int tap = 0; tap < 9; ++tap) {
    // --- per-(pixel,tap) bilinear setup (validity & mask folded in) ---
    const int kh = tap / 3, kw = tap % 3;
    const float py = (float)(h + kh - 1) + pmp[2 * tap];
    const float px = (float)(w_ + kw - 1) + pmp[2 * tap + 1];
    const float mk = pmp[18 + tap];
    const float y0f = floorf(py), x0f = floorf(px);
    const float wy1 = py - y0f, wx1 = px - x0f;
    const float wy0 = 1.f - wy1, wx0 = 1.f - wx1;
    const bool vy0 = (y0f >= 0.f) && (y0f <= (float)(IH - 1));
    const bool vy1 = (y0f + 1.f >= 0.f) && (y0f + 1.f <= (float)(IH - 1));
    const bool vx0 = (x0f >= 0.f) && (x0f <= (float)(IW - 1));
    const bool vx1 = (x0f + 1.f >= 0.f) && (x0f + 1.f <= (float)(IW - 1));
    const int iy0 = min(max((int)y0f, 0), IH - 1);
    const int iy1 = min(max((int)y0f + 1, 0), IH - 1);
    const int ix0 = min(max((int)x0f, 0), IW - 1);
    const int ix1 = min(max((int)x0f + 1, 0), IW - 1);
    const float w00 = wy0 * wx0 * mk * ((vy0 && vx0) ? 1.f : 0.f);
    const float w01 = wy0 * wx1 * mk * ((vy0 && vx1) ? 1.f : 0.f);
    const float w10 = wy1 * wx0 * mk * ((vy1 && vx0) ? 1.f : 0.f);
    const float w11 = wy1 * wx1 * mk * ((vy1 && vx1) ? 1.f : 0.f);
    const float* r0 = xb + iy0 * IW;
    const float* r1 = xb + iy1 * IW;

    // --- build all 4 A-frags for this tap (registers only) ---
    short8 afr[4];
    #pragma unroll
    for (int kq = 0; kq < 4; ++kq) {
      const int cbase = kq * 32 + q * 8;
      #pragma unroll
      for (int j = 0; j < 8; ++j) {
        const int coff = (cbase + j) * HW;
        float v = w00 * r0[coff + ix0] + w01 * r0[coff + ix1]
                + w10 * r1[coff + ix0] + w11 * r1[coff + ix1];
        afr[kq][j] = f2bf(v);
      }
    }

    // --- two 128-row halves of B through LDS ---
    #pragma unroll
    for (int hf = 0; hf < 2; ++hf) {
      __syncthreads();
      {
        const uintx4* src = (const uintx4*)(Bt2 + (size_t)(tap * 2 + hf) * 128 * BST);
        uintx4* dst = (uintx4*)blds;
        for (int i = tid; i < 128 * BST * 2 / 16; i += 256) dst[i] = src[i];
      }
      __syncthreads();
      #pragma unroll
      for (int kq = 0; kq < 4; ++kq) {
        const int cbase = kq * 32 + q * 8;
        #pragma unroll
        for (int nl = 0; nl < 8; ++nl) {
          const short8* bf = (const short8*)(blds + (nl * 16 + m) * BST + cbase);
          acc[hf * 8 + nl] =
              __builtin_amdgcn_mfma_f32_16x16x32_bf16(afr[kq], *bf, acc[hf * 8 + nl], 0, 0, 0);
        }
      }
    }
  }

  // --- epilogue: LDS transpose for coalesced stores, + bias ---
  const int hw0 = p0 % HW;
  #pragma unroll
  for (int hf = 0; hf < 2; ++hf) {
    __syncthreads();
    #pragma unroll
    for (int nl = 0; nl < 8; ++nl) {
      const int ol = nl * 16 + m;           // o within this 128-half
      #pragma unroll
      for (int r = 0; r < 4; ++r)
        elds[ol * 65 + wv * 16 + q * 4 + r] = acc[hf * 8 + nl][r];
    }
    __syncthreads();
    for (int i = 0; i < 32; ++i) {
      const int ol = wv * 32 + i;
      const int o  = hf * 128 + ol;
      out[(size_t)(b * COUT + o) * HW + hw0 + lane] = elds[ol * 65 + lane] + bias[o];
    }
  }
}

// ---------------------------------------------------------------------------
extern "C" void kernel_launch(void* const* d_in, const int* in_sizes, int n_in,
                              void* d_out, int out_size, void* d_ws, size_t ws_size,
                              hipStream_t stream) {
  const float* x        = (const float*)d_in[0];
  const float* offset_w = (const float*)d_in[1];
  const float* offset_b = (const float*)d_in[2];
  const float* mask_w   = (const float*)d_in[3];
  const float* mask_b   = (const float*)d_in[4];
  const float* weight   = (const float*)d_in[5];
  const float* bias     = (const float*)d_in[6];
  float* out = (float*)d_out;

  char* ws = (char*)d_ws;
  const size_t PM_BYTES  = (size_t)NPIX * 32 * 4;       // 9,437,184
  const size_t BT2_BYTES = (size_t)9 * COUT * BST * 2;  //   626,688
  float* pm  = (float*)ws;
  short* Bt2 = (short*)(ws + PM_BYTES);
  short* Bt1 = (short*)(ws + PM_BYTES + BT2_BYTES);

  // kernel 0: weight repack (exactly covers 9*256*136 + 9*32*136 elems)
  prep_weights<<<dim3(1377), dim3(256), 0, stream>>>(weight, offset_w, mask_w, Bt2, Bt1);
  // kernel 1: offset/mask conv -> pm[pixel][32]
  offmask_kernel<<<dim3(NPIX / 64), dim3(256), 0, stream>>>(x, Bt1, offset_b, mask_b, pm);
  // kernel 2: fused sampling + deformable GEMM
  deform_main<<<dim3(NPIX / 64), dim3(256), 0, stream>>>(x, Bt2, pm, bias, out);
}

// Round 2
// 419.743 us; speedup vs baseline: 1.7085x; 1.7085x over previous
//
#include <hip/hip_runtime.h>

#define CIN 128
#define COUT 256
#define IH 96
#define IW 96
#define NB 8
#define HW (IH*IW)          // 9216
#define NPIX (NB*HW)        // 73728
#define BST 136             // padded k-stride (bf16 elems) for B tiles

typedef __attribute__((ext_vector_type(8))) short short8;
typedef __attribute__((ext_vector_type(4))) float floatx4;
typedef __attribute__((ext_vector_type(4))) unsigned int uintx4;

static __device__ __forceinline__ short f2bf(float f) {
  unsigned int u = __builtin_bit_cast(unsigned int, f);
  u = u + 0x7fffu + ((u >> 16) & 1u);
  return (short)(u >> 16);
}
static __device__ __forceinline__ float bf2f(short s) {
  unsigned int u = ((unsigned int)(unsigned short)s) << 16;
  return __builtin_bit_cast(float, u);
}

// ---------------------------------------------------------------------------
// Kernel 0: repack conv weights to bf16, [tap][row n][k=c] with k-stride BST.
// ---------------------------------------------------------------------------
__global__ void prep_weights(const float* __restrict__ weight,
                             const float* __restrict__ offset_w,
                             const float* __restrict__ mask_w,
                             short* __restrict__ Bt2,
                             short* __restrict__ Bt1) {
  int idx = blockIdx.x * 256 + threadIdx.x;
  const int n2 = 9 * COUT * BST;
  if (idx < n2) {
    int c = idx % BST;
    int t = idx / BST;
    int o = t % COUT, tap = t / COUT;
    float v = (c < CIN) ? weight[(o * CIN + c) * 9 + tap] : 0.f;
    Bt2[idx] = f2bf(v);
  } else {
    int j = idx - n2;
    const int n1 = 9 * 32 * BST;
    if (j < n1) {
      int c = j % BST;
      int t = j / BST;
      int n = t % 32, tap = t / 32;
      float v = 0.f;
      if (c < CIN && n < 27)
        v = (n < 18) ? offset_w[(n * CIN + c) * 9 + tap]
                     : mask_w[((n - 18) * CIN + c) * 9 + tap];
      Bt1[j] = f2bf(v);
    }
  }
}

// ---------------------------------------------------------------------------
// Kernel 0b: transpose x NCHW fp32 -> NHWC bf16.  Block = 64 pixels x 128 ch.
// Coalesced reads (64 px along hw), coalesced uint writes (ch-major), LDS
// tile stride 130 shorts (65 words -> bank stride 1, conflict-free).
// ---------------------------------------------------------------------------
__global__ __launch_bounds__(256, 8)
void transpose_x(const float* __restrict__ x, short* __restrict__ xt) {
  __shared__ short tile[64 * 130];
  const int tid = threadIdx.x;
  const int lane = tid & 63;
  const int wv = tid >> 6;
  const int p0 = blockIdx.x * 64;
  const int b = p0 / HW;
  const int hw0 = p0 % HW;
  const float* xb = x + (size_t)b * CIN * HW + hw0;

  #pragma unroll
  for (int i = 0; i < 32; ++i) {
    int c = wv + i * 4;
    tile[lane * 130 + c] = f2bf(xb[(size_t)c * HW + lane]);
  }
  __syncthreads();

  unsigned int* dst = (unsigned int*)(xt + ((size_t)b * HW + hw0) * 128);
  #pragma unroll
  for (int i = 0; i < 16; ++i) {
    int idx = i * 256 + tid;
    int px = idx >> 6, cw = idx & 63;
    unsigned int lo = (unsigned short)tile[px * 130 + 2 * cw];
    unsigned int hi = (unsigned short)tile[px * 130 + 2 * cw + 1];
    dst[idx] = lo | (hi << 16);
  }
}

// ---------------------------------------------------------------------------
// Kernel 1: offset+mask conv via MFMA.  A-frags = direct short8 loads from
// NHWC-bf16 xt (zero outside border).  Out: pm[pixel][32] fp32.
// ---------------------------------------------------------------------------
__global__ __launch_bounds__(256, 8)
void offmask_kernel(const short* __restrict__ xt,
                    const short* __restrict__ Bt1,
                    const float* __restrict__ offset_b,
                    const float* __restrict__ mask_b,
                    float* __restrict__ pm) {
  __shared__ short blds[32 * BST];          // 8704 B

  const int tid  = threadIdx.x;
  const int lane = tid & 63;
  const int wv   = tid >> 6;
  const int q    = lane >> 4;
  const int m    = lane & 15;
  const int p0   = blockIdx.x * 64;
  const int b    = p0 / HW;
  const int p    = p0 + wv * 16 + m;
  const int hw   = p % HW;
  const int h    = hw / IW, w_ = hw % IW;
  const short* xtb = xt + (size_t)b * HW * 128;

  floatx4 acc[2];
  acc[0] = (floatx4){0.f, 0.f, 0.f, 0.f};
  acc[1] = (floatx4){0.f, 0.f, 0.f, 0.f};

  for (int tap = 0; tap < 9; ++tap) {
    __syncthreads();
    {
      const uintx4* src = (const uintx4*)(Bt1 + tap * 32 * BST);
      uintx4* dst = (uintx4*)blds;
      for (int i = tid; i < 32 * BST * 2 / 16; i += 256) dst[i] = src[i];
    }
    __syncthreads();

    const int kh = tap / 3, kw = tap % 3;
    const int iy = h + kh - 1, ix = w_ + kw - 1;
    const bool vald = (iy >= 0 && iy < IH && ix >= 0 && ix < IW);
    const size_t pbase = vald ? (size_t)(iy * IW + ix) * 128 : 0;

    #pragma unroll
    for (int kq = 0; kq < 4; ++kq) {
      const int cbase = kq * 32 + q * 8;
      short8 a = *(const short8*)(xtb + pbase + cbase);
      if (!vald) a = (short8){0, 0, 0, 0, 0, 0, 0, 0};
      #pragma unroll
      for (int ni = 0; ni < 2; ++ni) {
        const short8* bf = (const short8*)(blds + (ni * 16 + m) * BST + cbase);
        acc[ni] = __builtin_amdgcn_mfma_f32_16x16x32_bf16(a, *bf, acc[ni], 0, 0, 0);
      }
    }
  }

  #pragma unroll
  for (int ni = 0; ni < 2; ++ni) {
    int ch = ni * 16 + m;
    if (ch < 27) {
      float cb = (ch < 18) ? offset_b[ch] : mask_b[ch - 18];
      #pragma unroll
      for (int r = 0; r < 4; ++r) {
        int pp = p0 + wv * 16 + q * 4 + r;
        float v = acc[ni][r] + cb;
        if (ch >= 18) v = 1.f / (1.f + expf(-v));
        pm[(size_t)pp * 32 + ch] = v;
      }
    }
  }
}

// ---------------------------------------------------------------------------
// Kernel 2: fused bilinear sampling + deformable GEMM.
// A-frags: 4-corner short8 loads from NHWC-bf16 xt, fp32 interp (mask &
// validity folded into the 4 weights), repack to bf16.  B via LDS halves.
// ---------------------------------------------------------------------------
__global__ __launch_bounds__(256, 4)
void deform_main(const short* __restrict__ xt,
                 const short* __restrict__ Bt2,
                 const float* __restrict__ pm,
                 const float* __restrict__ bias,
                 float* __restrict__ out) {
  __shared__ short blds[128 * BST];         // 34816 B
  float* elds = (float*)blds;               // epilogue reuse

  const int tid  = threadIdx.x;
  const int lane = tid & 63;
  const int wv   = tid >> 6;
  const int q    = lane >> 4;
  const int m    = lane & 15;
  const int p0   = blockIdx.x * 64;
  const int b    = p0 / HW;
  const int p    = p0 + wv * 16 + m;
  const int hw   = p % HW;
  const int h    = hw / IW, w_ = hw % IW;
  const short* xtb = xt + (size_t)b * HW * 128;
  const float* pmp = pm + (size_t)p * 32;

  floatx4 acc[16];
  #pragma unroll
  for (int i = 0; i < 16; ++i) acc[i] = (floatx4){0.f, 0.f, 0.f, 0.f};

  for (int tap = 0; tap < 9; ++tap) {
    const int kh = tap / 3, kw = tap % 3;
    const float py = (float)(h + kh - 1) + pmp[2 * tap];
    const float px = (float)(w_ + kw - 1) + pmp[2 * tap + 1];
    const float mk = pmp[18 + tap];
    const float y0f = floorf(py), x0f = floorf(px);
    const float wy1 = py - y0f, wx1 = px - x0f;
    const float wy0 = 1.f - wy1, wx0 = 1.f - wx1;
    const bool vy0 = (y0f >= 0.f) && (y0f <= (float)(IH - 1));
    const bool vy1 = (y0f + 1.f >= 0.f) && (y0f + 1.f <= (float)(IH - 1));
    const bool vx0 = (x0f >= 0.f) && (x0f <= (float)(IW - 1));
    const bool vx1 = (x0f + 1.f >= 0.f) && (x0f + 1.f <= (float)(IW - 1));
    const int iy0 = min(max((int)y0f, 0), IH - 1);
    const int iy1 = min(max((int)y0f + 1, 0), IH - 1);
    const int ix0 = min(max((int)x0f, 0), IW - 1);
    const int ix1 = min(max((int)x0f + 1, 0), IW - 1);
    const float w00 = wy0 * wx0 * mk * ((vy0 && vx0) ? 1.f : 0.f);
    const float w01 = wy0 * wx1 * mk * ((vy0 && vx1) ? 1.f : 0.f);
    const float w10 = wy1 * wx0 * mk * ((vy1 && vx0) ? 1.f : 0.f);
    const float w11 = wy1 * wx1 * mk * ((vy1 && vx1) ? 1.f : 0.f);
    const size_t b00 = (size_t)(iy0 * IW + ix0) * 128;
    const size_t b01 = (size_t)(iy0 * IW + ix1) * 128;
    const size_t b10 = (size_t)(iy1 * IW + ix0) * 128;
    const size_t b11 = (size_t)(iy1 * IW + ix1) * 128;

    // --- A-frags: 4 x dwordx4 per kq, fp32 interp, pack to bf16 ---
    short8 afr[4];
    #pragma unroll
    for (int kq = 0; kq < 4; ++kq) {
      const int cb = kq * 32 + q * 8;
      short8 s00 = *(const short8*)(xtb + b00 + cb);
      short8 s01 = *(const short8*)(xtb + b01 + cb);
      short8 s10 = *(const short8*)(xtb + b10 + cb);
      short8 s11 = *(const short8*)(xtb + b11 + cb);
      #pragma unroll
      for (int j = 0; j < 8; ++j) {
        float v = w00 * bf2f(s00[j]) + w01 * bf2f(s01[j])
                + w10 * bf2f(s10[j]) + w11 * bf2f(s11[j]);
        afr[kq][j] = f2bf(v);
      }
    }

    // --- two 128-row halves of B through LDS ---
    #pragma unroll
    for (int hf = 0; hf < 2; ++hf) {
      __syncthreads();
      {
        const uintx4* src = (const uintx4*)(Bt2 + (size_t)(tap * 2 + hf) * 128 * BST);
        uintx4* dst = (uintx4*)blds;
        for (int i = tid; i < 128 * BST * 2 / 16; i += 256) dst[i] = src[i];
      }
      __syncthreads();
      #pragma unroll
      for (int kq = 0; kq < 4; ++kq) {
        const int cbase = kq * 32 + q * 8;
        #pragma unroll
        for (int nl = 0; nl < 8; ++nl) {
          const short8* bf = (const short8*)(blds + (nl * 16 + m) * BST + cbase);
          acc[hf * 8 + nl] =
              __builtin_amdgcn_mfma_f32_16x16x32_bf16(afr[kq], *bf, acc[hf * 8 + nl], 0, 0, 0);
        }
      }
    }
  }

  // --- epilogue: LDS transpose for coalesced stores, + bias ---
  const int hw0 = p0 % HW;
  #pragma unroll
  for (int hf = 0; hf < 2; ++hf) {
    __syncthreads();
    #pragma unroll
    for (int nl = 0; nl < 8; ++nl) {
      const int ol = nl * 16 + m;
      #pragma unroll
      for (int r = 0; r < 4; ++r)
        elds[ol * 65 + wv * 16 + q * 4 + r] = acc[hf * 8 + nl][r];
    }
    __syncthreads();
    for (int i = 0; i < 32; ++i) {
      const int ol = wv * 32 + i;
      const int o  = hf * 128 + ol;
      out[(size_t)(b * COUT + o) * HW + hw0 + lane] = elds[ol * 65 + lane] + bias[o];
    }
  }
}

// ---------------------------------------------------------------------------
extern "C" void kernel_launch(void* const* d_in, const int* in_sizes, int n_in,
                              void* d_out, int out_size, void* d_ws, size_t ws_size,
                              hipStream_t stream) {
  const float* x        = (const float*)d_in[0];
  const float* offset_w = (const float*)d_in[1];
  const float* offset_b = (const float*)d_in[2];
  const float* mask_w   = (const float*)d_in[3];
  const float* mask_b   = (const float*)d_in[4];
  const float* weight   = (const float*)d_in[5];
  const float* bias     = (const float*)d_in[6];
  float* out = (float*)d_out;

  char* ws = (char*)d_ws;
  const size_t XT_BYTES  = (size_t)NPIX * 128 * 2;      // 18,874,368
  const size_t PM_BYTES  = (size_t)NPIX * 32 * 4;       //  9,437,184
  const size_t BT2_BYTES = (size_t)9 * COUT * BST * 2;  //    626,688
  short* xtp = (short*)ws;
  float* pm  = (float*)(ws + XT_BYTES);
  short* Bt2 = (short*)(ws + XT_BYTES + PM_BYTES);
  short* Bt1 = (short*)(ws + XT_BYTES + PM_BYTES + BT2_BYTES);

  prep_weights<<<dim3(1377), dim3(256), 0, stream>>>(weight, offset_w, mask_w, Bt2, Bt1);
  transpose_x<<<dim3(NPIX / 64), dim3(256), 0, stream>>>(x, xtp);
  offmask_kernel<<<dim3(NPIX / 64), dim3(256), 0, stream>>>(xtp, Bt1, offset_b, mask_b, pm);
  deform_main<<<dim3(NPIX / 64), dim3(256), 0, stream>>>(xtp, Bt2, pm, bias, out);
}

// Round 3
// 266.825 us; speedup vs baseline: 2.6876x; 1.5731x over previous
//
#include <hip/hip_runtime.h>

#define CIN 128
#define COUT 256
#define IH 96
#define IW 96
#define NB 8
#define HW (IH*IW)          // 9216
#define NPIX (NB*HW)        // 73728
#define AST 136             // LDS A-tile row stride (shorts): 272 B, 16B-aligned
#define BLK_PER_IMG (HW/64) // 144

typedef __attribute__((ext_vector_type(8))) short short8;
typedef __attribute__((ext_vector_type(4))) float floatx4;

static __device__ __forceinline__ short f2bf(float f) {
  unsigned int u = __builtin_bit_cast(unsigned int, f);
  u = u + 0x7fffu + ((u >> 16) & 1u);
  return (short)(u >> 16);
}
static __device__ __forceinline__ float bf2f(short s) {
  unsigned int u = ((unsigned int)(unsigned short)s) << 16;
  return __builtin_bit_cast(float, u);
}

// ---------------------------------------------------------------------------
// Kernel 0: pack weights into FRAGMENT-LINEAR bf16 streams.
//  Bt2f[((tap*4+kq)*16 + nl)*512 + lane*8 + e] = W[o=nl*16+(lane&15)]
//                                                 [c=kq*32+(lane>>4)*8+e][tap]
//  Bt1f: same with nl in {0,1}, rows 0..17 offset_w, 18..26 mask_w, else 0.
// Every GEMM B-load becomes a fully-coalesced 1KB dwordx4 stream.
// ---------------------------------------------------------------------------
__global__ void prep_weights(const float* __restrict__ weight,
                             const float* __restrict__ offset_w,
                             const float* __restrict__ mask_w,
                             short* __restrict__ Bt2f,
                             short* __restrict__ Bt1f) {
  int idx = blockIdx.x * 256 + threadIdx.x;
  const int n2 = 9 * 4 * 16 * 512;          // 294912
  if (idx < n2) {
    int e = idx & 7, lane = (idx >> 3) & 63;
    int g = idx >> 9;
    int nl = g & 15, kq = (g >> 4) & 3, tap = g >> 6;
    int o = nl * 16 + (lane & 15);
    int c = kq * 32 + (lane >> 4) * 8 + e;
    Bt2f[idx] = f2bf(weight[(o * CIN + c) * 9 + tap]);
  } else {
    int j = idx - n2;
    if (j < 9 * 4 * 2 * 512) {              // 36864
      int e = j & 7, lane = (j >> 3) & 63;
      int g = j >> 9;
      int nl = g & 1, kq = (g >> 1) & 3, tap = g >> 3;
      int n = nl * 16 + (lane & 15);
      int c = kq * 32 + (lane >> 4) * 8 + e;
      float v = 0.f;
      if (n < 27)
        v = (n < 18) ? offset_w[(n * CIN + c) * 9 + tap]
                     : mask_w[((n - 18) * CIN + c) * 9 + tap];
      Bt1f[j] = f2bf(v);
    }
  }
}

// ---------------------------------------------------------------------------
// Kernel 0b: transpose x NCHW fp32 -> NHWC bf16 (unchanged from R2).
// ---------------------------------------------------------------------------
__global__ __launch_bounds__(256, 8)
void transpose_x(const float* __restrict__ x, short* __restrict__ xt) {
  __shared__ short tile[64 * 130];
  const int tid = threadIdx.x;
  const int lane = tid & 63;
  const int wv = tid >> 6;
  const int p0 = blockIdx.x * 64;
  const int b = p0 / HW;
  const int hw0 = p0 % HW;
  const float* xb = x + (size_t)b * CIN * HW + hw0;

  #pragma unroll
  for (int i = 0; i < 32; ++i) {
    int c = wv + i * 4;
    tile[lane * 130 + c] = f2bf(xb[(size_t)c * HW + lane]);
  }
  __syncthreads();

  unsigned int* dst = (unsigned int*)(xt + ((size_t)b * HW + hw0) * 128);
  #pragma unroll
  for (int i = 0; i < 16; ++i) {
    int idx = i * 256 + tid;
    int px = idx >> 6, cw = idx & 63;
    unsigned int lo = (unsigned short)tile[px * 130 + 2 * cw];
    unsigned int hi = (unsigned short)tile[px * 130 + 2 * cw + 1];
    dst[idx] = lo | (hi << 16);
  }
}

// ---------------------------------------------------------------------------
// Kernel 1: offset+mask conv.  NO LDS, NO barriers: waves split M (16 px),
// B-frags stream from L2 frag-linear.  Epilogue writes pm PLANES with the
// base sampling coordinate folded in:
//   pmt[(0*9+tap)*NPIX + p] = y-coord, [(9+tap)] = x-coord, [(18+tap)] = mask.
// ---------------------------------------------------------------------------
__global__ __launch_bounds__(256, 8)
void offmask_kernel(const short* __restrict__ xt,
                    const short* __restrict__ Bt1f,
                    const float* __restrict__ offset_b,
                    const float* __restrict__ mask_b,
                    float* __restrict__ pmt) {
  const int tid  = threadIdx.x;
  const int lane = tid & 63;
  const int wv   = tid >> 6;
  const int q    = lane >> 4;
  const int m    = lane & 15;
  const int blk  = blockIdx.x;
  const int l    = (blk & 7) * BLK_PER_IMG + (blk >> 3);   // XCD->image locality
  const int p0   = l * 64;
  const int b    = p0 / HW;
  const int p    = p0 + wv * 16 + m;
  const int hw   = p % HW;
  const int h    = hw / IW, w_ = hw % IW;
  const short* xtb = xt + (size_t)b * HW * 128;

  floatx4 acc0 = (floatx4){0.f, 0.f, 0.f, 0.f};
  floatx4 acc1 = (floatx4){0.f, 0.f, 0.f, 0.f};

  for (int tap = 0; tap < 9; ++tap) {
    const int kh = tap / 3, kw = tap % 3;
    const int iy = h + kh - 1, ix = w_ + kw - 1;
    const bool vald = (iy >= 0 && iy < IH && ix >= 0 && ix < IW);
    const size_t pbase = vald ? (size_t)(iy * IW + ix) * 128 : 0;
    #pragma unroll
    for (int kq = 0; kq < 4; ++kq) {
      short8 a = *(const short8*)(xtb + pbase + kq * 32 + q * 8);
      if (!vald) a = (short8){0, 0, 0, 0, 0, 0, 0, 0};
      const short8* b0 = (const short8*)(Bt1f + (size_t)((tap * 4 + kq) * 2 + 0) * 512 + lane * 8);
      const short8* b1 = (const short8*)(Bt1f + (size_t)((tap * 4 + kq) * 2 + 1) * 512 + lane * 8);
      acc0 = __builtin_amdgcn_mfma_f32_16x16x32_bf16(a, *b0, acc0, 0, 0, 0);
      acc1 = __builtin_amdgcn_mfma_f32_16x16x32_bf16(a, *b1, acc1, 0, 0, 0);
    }
  }

  #pragma unroll
  for (int nl = 0; nl < 2; ++nl) {
    floatx4 ac = nl ? acc1 : acc0;
    int ch = nl * 16 + m;
    if (ch < 18) {
      int tap = ch >> 1, plane = ch & 1;
      float cb = offset_b[ch];
      #pragma unroll
      for (int r = 0; r < 4; ++r) {
        int pp = p0 + wv * 16 + q * 4 + r;
        int hwp = pp % HW;
        float base = plane ? (float)(hwp % IW + tap % 3 - 1)
                           : (float)(hwp / IW + tap / 3 - 1);
        pmt[(size_t)(plane * 9 + tap) * NPIX + pp] = ac[r] + cb + base;
      }
    } else if (ch < 27) {
      int tap = ch - 18;
      float cb = mask_b[tap];
      #pragma unroll
      for (int r = 0; r < 4; ++r) {
        int pp = p0 + wv * 16 + q * 4 + r;
        float v = ac[r] + cb;
        pmt[(size_t)(18 + tap) * NPIX + pp] = 1.f / (1.f + expf(-v));
      }
    }
  }
}

// ---------------------------------------------------------------------------
// Kernel 2: fused sampling + deformable GEMM, restructured.
//  Block = 64 px x 256 out.  Waves split N (wave wv: outputs wv*64..+63).
//  A-tile (64 px x 128 ch bf16 samples) staged in double-buffered LDS: each
//  thread samples pixel (tid&63), channel oct wv*4+i.  ONE barrier per tap.
//  B-frags stream from L2 (frag-linear, 1KB coalesced loads, no LDS).
//  Epilogue: direct dwordx4 stores (D rows = 4 consecutive pixels).
// ---------------------------------------------------------------------------
__global__ __launch_bounds__(256, 3)
void deform_main(const short* __restrict__ xt,
                 const short* __restrict__ Bt2f,
                 const float* __restrict__ pmt,
                 const float* __restrict__ bias,
                 float* __restrict__ out) {
  __shared__ short Ald[2][64 * AST];        // 2 x 17408 B = 34816 B

  const int tid  = threadIdx.x;
  const int lane = tid & 63;
  const int wv   = tid >> 6;
  const int q    = lane >> 4;
  const int m    = lane & 15;
  const int blk  = blockIdx.x;
  const int l    = (blk & 7) * BLK_PER_IMG + (blk >> 3);   // XCD->image locality
  const int p0   = l * 64;
  const int b    = p0 / HW;
  const short* xtb = xt + (size_t)b * HW * 128;

  // staging geometry: this thread samples pixel spx, channel octs wv*4+i
  const int spx = lane;
  const int p_s = p0 + spx;
  const int choff = wv * 32;                // shorts

  floatx4 acc[4][4];
  #pragma unroll
  for (int i = 0; i < 4; ++i)
    #pragma unroll
    for (int j = 0; j < 4; ++j) acc[i][j] = (floatx4){0.f, 0.f, 0.f, 0.f};

  // ---- stage one tap's A-tile into buf ----
  auto stage_tap = [&](int t, short* buf) {
    float py = pmt[(size_t)t * NPIX + p_s];          // base + offset (folded)
    float px = pmt[(size_t)(9 + t) * NPIX + p_s];
    float mk = pmt[(size_t)(18 + t) * NPIX + p_s];
    float y0f = floorf(py), x0f = floorf(px);
    float wy1 = py - y0f, wx1 = px - x0f;
    float wy0 = 1.f - wy1, wx0 = 1.f - wx1;
    bool vy0 = (y0f >= 0.f) && (y0f <= (float)(IH - 1));
    bool vy1 = (y0f + 1.f >= 0.f) && (y0f + 1.f <= (float)(IH - 1));
    bool vx0 = (x0f >= 0.f) && (x0f <= (float)(IW - 1));
    bool vx1 = (x0f + 1.f >= 0.f) && (x0f + 1.f <= (float)(IW - 1));
    int iy0 = min(max((int)y0f, 0), IH - 1);
    int iy1 = min(max((int)y0f + 1, 0), IH - 1);
    int ix0 = min(max((int)x0f, 0), IW - 1);
    int ix1 = min(max((int)x0f + 1, 0), IW - 1);
    float w00 = wy0 * wx0 * mk * ((vy0 && vx0) ? 1.f : 0.f);
    float w01 = wy0 * wx1 * mk * ((vy0 && vx1) ? 1.f : 0.f);
    float w10 = wy1 * wx0 * mk * ((vy1 && vx0) ? 1.f : 0.f);
    float w11 = wy1 * wx1 * mk * ((vy1 && vx1) ? 1.f : 0.f);
    const short* r00 = xtb + (size_t)(iy0 * IW + ix0) * 128 + choff;
    const short* r01 = xtb + (size_t)(iy0 * IW + ix1) * 128 + choff;
    const short* r10 = xtb + (size_t)(iy1 * IW + ix0) * 128 + choff;
    const short* r11 = xtb + (size_t)(iy1 * IW + ix1) * 128 + choff;
    short* dst = buf + spx * AST + choff;
    #pragma unroll
    for (int i = 0; i < 4; ++i) {
      short8 s00 = *(const short8*)(r00 + i * 8);
      short8 s01 = *(const short8*)(r01 + i * 8);
      short8 s10 = *(const short8*)(r10 + i * 8);
      short8 s11 = *(const short8*)(r11 + i * 8);
      short8 o;
      #pragma unroll
      for (int j = 0; j < 8; ++j) {
        float v = w00 * bf2f(s00[j]) + w01 * bf2f(s01[j])
                + w10 * bf2f(s10[j]) + w11 * bf2f(s11[j]);
        o[j] = f2bf(v);
      }
      *(short8*)(dst + i * 8) = o;
    }
  };

  stage_tap(0, Ald[0]);
  __syncthreads();

  for (int tap = 0; tap < 9; ++tap) {
    const short* bufr = Ald[tap & 1];
    #pragma unroll
    for (int kq = 0; kq < 4; ++kq) {
      short8 af[4];
      #pragma unroll
      for (int mt = 0; mt < 4; ++mt)
        af[mt] = *(const short8*)(bufr + (mt * 16 + m) * AST + kq * 32 + q * 8);
      short8 bf[4];
      #pragma unroll
      for (int nl = 0; nl < 4; ++nl)
        bf[nl] = *(const short8*)(Bt2f + (size_t)((tap * 4 + kq) * 16 + wv * 4 + nl) * 512 + lane * 8);
      #pragma unroll
      for (int mt = 0; mt < 4; ++mt)
        #pragma unroll
        for (int nl = 0; nl < 4; ++nl)
          acc[mt][nl] = __builtin_amdgcn_mfma_f32_16x16x32_bf16(af[mt], bf[nl], acc[mt][nl], 0, 0, 0);
    }
    if (tap < 8) stage_tap(tap + 1, Ald[(tap + 1) & 1]);
    __syncthreads();
  }

  // ---- epilogue: direct stores.  D: row=q*4+r -> px mt*16+q*4+r, col=m ----
  const int hw0 = p0 % HW;
  #pragma unroll
  for (int nl = 0; nl < 4; ++nl) {
    const int o = wv * 64 + nl * 16 + m;
    const float bs = bias[o];
    float* op = out + (size_t)(b * COUT + o) * HW + hw0;
    #pragma unroll
    for (int mt = 0; mt < 4; ++mt) {
      floatx4 v = acc[mt][nl];
      v[0] += bs; v[1] += bs; v[2] += bs; v[3] += bs;
      *(floatx4*)(op + mt * 16 + q * 4) = v;
    }
  }
}

// ---------------------------------------------------------------------------
extern "C" void kernel_launch(void* const* d_in, const int* in_sizes, int n_in,
                              void* d_out, int out_size, void* d_ws, size_t ws_size,
                              hipStream_t stream) {
  const float* x        = (const float*)d_in[0];
  const float* offset_w = (const float*)d_in[1];
  const float* offset_b = (const float*)d_in[2];
  const float* mask_w   = (const float*)d_in[3];
  const float* mask_b   = (const float*)d_in[4];
  const float* weight   = (const float*)d_in[5];
  const float* bias     = (const float*)d_in[6];
  float* out = (float*)d_out;

  char* ws = (char*)d_ws;
  const size_t XT_BYTES  = (size_t)NPIX * 128 * 2;        // 18,874,368
  const size_t PMT_BYTES = (size_t)27 * NPIX * 4;         //  7,962,624
  const size_t BT2_BYTES = (size_t)9 * 4 * 16 * 512 * 2;  //    589,824
  short* xtp  = (short*)ws;
  float* pmt  = (float*)(ws + XT_BYTES);
  short* Bt2f = (short*)(ws + XT_BYTES + PMT_BYTES);
  short* Bt1f = (short*)(ws + XT_BYTES + PMT_BYTES + BT2_BYTES);

  prep_weights<<<dim3(1296), dim3(256), 0, stream>>>(weight, offset_w, mask_w, Bt2f, Bt1f);
  transpose_x<<<dim3(NPIX / 64), dim3(256), 0, stream>>>(x, xtp);
  offmask_kernel<<<dim3(NPIX / 64), dim3(256), 0, stream>>>(xtp, Bt1f, offset_b, mask_b, pmt);
  deform_main<<<dim3(NPIX / 64), dim3(256), 0, stream>>>(xtp, Bt2f, pmt, bias, out);
}

// Round 4
// 257.805 us; speedup vs baseline: 2.7817x; 1.0350x over previous
//
#include <hip/hip_runtime.h>

#define CIN 128
#define COUT 256
#define IH 96
#define IW 96
#define NB 8
#define HW (IH*IW)          // 9216
#define NPIX (NB*HW)        // 73728
#define AST 136             // LDS A-tile row stride (shorts)
#define BLK_PER_IMG (HW/64) // 144

typedef __attribute__((ext_vector_type(8))) short short8;
typedef __attribute__((ext_vector_type(4))) float floatx4;

static __device__ __forceinline__ short f2bf(float f) {
  unsigned int u = __builtin_bit_cast(unsigned int, f);
  u = u + 0x7fffu + ((u >> 16) & 1u);
  return (short)(u >> 16);
}
static __device__ __forceinline__ float bf2f(short s) {
  unsigned int u = ((unsigned int)(unsigned short)s) << 16;
  return __builtin_bit_cast(float, u);
}

struct Corner {
  float w00, w01, w10, w11;
  const short *r00, *r01, *r10, *r11;
};

// bilinear corner weights (validity & mask folded) + NHWC row pointers
static __device__ __forceinline__ Corner corner_setup(float py, float px, float mk,
                                                      const short* xtb, int choff) {
  Corner c;
  float y0f = floorf(py), x0f = floorf(px);
  float wy1 = py - y0f, wx1 = px - x0f;
  float wy0 = 1.f - wy1, wx0 = 1.f - wx1;
  bool vy0 = (y0f >= 0.f) && (y0f <= (float)(IH - 1));
  bool vy1 = (y0f + 1.f >= 0.f) && (y0f + 1.f <= (float)(IH - 1));
  bool vx0 = (x0f >= 0.f) && (x0f <= (float)(IW - 1));
  bool vx1 = (x0f + 1.f >= 0.f) && (x0f + 1.f <= (float)(IW - 1));
  int iy0 = min(max((int)y0f, 0), IH - 1);
  int iy1 = min(max((int)y0f + 1, 0), IH - 1);
  int ix0 = min(max((int)x0f, 0), IW - 1);
  int ix1 = min(max((int)x0f + 1, 0), IW - 1);
  c.w00 = wy0 * wx0 * mk * ((vy0 && vx0) ? 1.f : 0.f);
  c.w01 = wy0 * wx1 * mk * ((vy0 && vx1) ? 1.f : 0.f);
  c.w10 = wy1 * wx0 * mk * ((vy1 && vx0) ? 1.f : 0.f);
  c.w11 = wy1 * wx1 * mk * ((vy1 && vx1) ? 1.f : 0.f);
  c.r00 = xtb + (size_t)(iy0 * IW + ix0) * 128 + choff;
  c.r01 = xtb + (size_t)(iy0 * IW + ix1) * 128 + choff;
  c.r10 = xtb + (size_t)(iy1 * IW + ix0) * 128 + choff;
  c.r11 = xtb + (size_t)(iy1 * IW + ix1) * 128 + choff;
  return c;
}

static __device__ __forceinline__ short8 interp8(short8 s00, short8 s01,
                                                 short8 s10, short8 s11,
                                                 const Corner& c) {
  short8 o;
  #pragma unroll
  for (int j = 0; j < 8; ++j) {
    float v = c.w00 * bf2f(s00[j]) + c.w01 * bf2f(s01[j])
            + c.w10 * bf2f(s10[j]) + c.w11 * bf2f(s11[j]);
    o[j] = f2bf(v);
  }
  return o;
}

// ---------------------------------------------------------------------------
// Kernel 0: pack weights into FRAGMENT-LINEAR bf16 streams (unchanged).
// ---------------------------------------------------------------------------
__global__ void prep_weights(const float* __restrict__ weight,
                             const float* __restrict__ offset_w,
                             const float* __restrict__ mask_w,
                             short* __restrict__ Bt2f,
                             short* __restrict__ Bt1f) {
  int idx = blockIdx.x * 256 + threadIdx.x;
  const int n2 = 9 * 4 * 16 * 512;          // 294912
  if (idx < n2) {
    int e = idx & 7, lane = (idx >> 3) & 63;
    int g = idx >> 9;
    int nl = g & 15, kq = (g >> 4) & 3, tap = g >> 6;
    int o = nl * 16 + (lane & 15);
    int c = kq * 32 + (lane >> 4) * 8 + e;
    Bt2f[idx] = f2bf(weight[(o * CIN + c) * 9 + tap]);
  } else {
    int j = idx - n2;
    if (j < 9 * 4 * 2 * 512) {              // 36864
      int e = j & 7, lane = (j >> 3) & 63;
      int g = j >> 9;
      int nl = g & 1, kq = (g >> 1) & 3, tap = g >> 3;
      int n = nl * 16 + (lane & 15);
      int c = kq * 32 + (lane >> 4) * 8 + e;
      float v = 0.f;
      if (n < 27)
        v = (n < 18) ? offset_w[(n * CIN + c) * 9 + tap]
                     : mask_w[((n - 18) * CIN + c) * 9 + tap];
      Bt1f[j] = f2bf(v);
    }
  }
}

// ---------------------------------------------------------------------------
// Kernel 0b: transpose x NCHW fp32 -> NHWC bf16 (unchanged).
// ---------------------------------------------------------------------------
__global__ __launch_bounds__(256, 8)
void transpose_x(const float* __restrict__ x, short* __restrict__ xt) {
  __shared__ short tile[64 * 130];
  const int tid = threadIdx.x;
  const int lane = tid & 63;
  const int wv = tid >> 6;
  const int p0 = blockIdx.x * 64;
  const int b = p0 / HW;
  const int hw0 = p0 % HW;
  const float* xb = x + (size_t)b * CIN * HW + hw0;

  #pragma unroll
  for (int i = 0; i < 32; ++i) {
    int c = wv + i * 4;
    tile[lane * 130 + c] = f2bf(xb[(size_t)c * HW + lane]);
  }
  __syncthreads();

  unsigned int* dst = (unsigned int*)(xt + ((size_t)b * HW + hw0) * 128);
  #pragma unroll
  for (int i = 0; i < 16; ++i) {
    int idx = i * 256 + tid;
    int px = idx >> 6, cw = idx & 63;
    unsigned int lo = (unsigned short)tile[px * 130 + 2 * cw];
    unsigned int hi = (unsigned short)tile[px * 130 + 2 * cw + 1];
    dst[idx] = lo | (hi << 16);
  }
}

// ---------------------------------------------------------------------------
// Kernel 1: offset+mask conv.  Per tap: issue ALL 12 loads (4 A + 8 B) with
// 12-deep ILP, one wait, 8 MFMAs.  launch_bounds(256,4) so VGPRs allow the
// in-flight loads (R3's (256,8)/VGPR=32 serialized every load -> 144 us).
// ---------------------------------------------------------------------------
__global__ __launch_bounds__(256, 4)
void offmask_kernel(const short* __restrict__ xt,
                    const short* __restrict__ Bt1f,
                    const float* __restrict__ offset_b,
                    const float* __restrict__ mask_b,
                    float* __restrict__ pmt) {
  const int tid  = threadIdx.x;
  const int lane = tid & 63;
  const int wv   = tid >> 6;
  const int q    = lane >> 4;
  const int m    = lane & 15;
  const int blk  = blockIdx.x;
  const int l    = (blk & 7) * BLK_PER_IMG + (blk >> 3);
  const int p0   = l * 64;
  const int b    = p0 / HW;
  const int p    = p0 + wv * 16 + m;
  const int hw   = p % HW;
  const int h    = hw / IW, w_ = hw % IW;
  const short* xtb = xt + (size_t)b * HW * 128;

  floatx4 acc0 = (floatx4){0.f, 0.f, 0.f, 0.f};
  floatx4 acc1 = (floatx4){0.f, 0.f, 0.f, 0.f};

  for (int tap = 0; tap < 9; ++tap) {
    const int kh = tap / 3, kw = tap % 3;
    const int iy = h + kh - 1, ix = w_ + kw - 1;
    const bool vald = (iy >= 0 && iy < IH && ix >= 0 && ix < IW);
    const size_t pbase = vald ? (size_t)(iy * IW + ix) * 128 : 0;

    short8 a[4], bb0[4], bb1[4];
    #pragma unroll
    for (int kq = 0; kq < 4; ++kq)
      a[kq] = *(const short8*)(xtb + pbase + kq * 32 + q * 8);
    #pragma unroll
    for (int kq = 0; kq < 4; ++kq) {
      bb0[kq] = *(const short8*)(Bt1f + (size_t)((tap * 4 + kq) * 2 + 0) * 512 + lane * 8);
      bb1[kq] = *(const short8*)(Bt1f + (size_t)((tap * 4 + kq) * 2 + 1) * 512 + lane * 8);
    }
    #pragma unroll
    for (int kq = 0; kq < 4; ++kq) {
      short8 av = a[kq];
      if (!vald) av = (short8){0, 0, 0, 0, 0, 0, 0, 0};
      acc0 = __builtin_amdgcn_mfma_f32_16x16x32_bf16(av, bb0[kq], acc0, 0, 0, 0);
      acc1 = __builtin_amdgcn_mfma_f32_16x16x32_bf16(av, bb1[kq], acc1, 0, 0, 0);
    }
  }

  #pragma unroll
  for (int nl = 0; nl < 2; ++nl) {
    floatx4 ac = nl ? acc1 : acc0;
    int ch = nl * 16 + m;
    if (ch < 18) {
      int tap = ch >> 1, plane = ch & 1;
      float cb = offset_b[ch];
      #pragma unroll
      for (int r = 0; r < 4; ++r) {
        int pp = p0 + wv * 16 + q * 4 + r;
        int hwp = pp % HW;
        float base = plane ? (float)(hwp % IW + tap % 3 - 1)
                           : (float)(hwp / IW + tap / 3 - 1);
        pmt[(size_t)(plane * 9 + tap) * NPIX + pp] = ac[r] + cb + base;
      }
    } else if (ch < 27) {
      int tap = ch - 18;
      float cb = mask_b[tap];
      #pragma unroll
      for (int r = 0; r < 4; ++r) {
        int pp = p0 + wv * 16 + q * 4 + r;
        float v = ac[r] + cb;
        pmt[(size_t)(18 + tap) * NPIX + pp] = 1.f / (1.f + expf(-v));
      }
    }
  }
}

// ---------------------------------------------------------------------------
// Kernel 2: fused sampling + deformable GEMM, chunk-level software pipeline.
//  Per tap t: B-frags loaded per kq (first, so their waits don't drain the
//  gathers), next-tap gather chunk kq issued, 16 MFMAs, then interp+LDS-write
//  of the PREVIOUS chunk (full kq-step of latency for each gather; interp
//  VALU co-issues with the MFMA pipe).  pmt prefetched one tap ahead.
//  LDS chunks XOR-swizzled by (px&3) -> staging writes & frag reads 2-way max.
// ---------------------------------------------------------------------------
__global__ __launch_bounds__(256, 3)
void deform_main(const short* __restrict__ xt,
                 const short* __restrict__ Bt2f,
                 const float* __restrict__ pmt,
                 const float* __restrict__ bias,
                 float* __restrict__ out) {
  __shared__ short Ald[2][64 * AST];        // 34816 B

  const int tid  = threadIdx.x;
  const int lane = tid & 63;
  const int wv   = tid >> 6;
  const int q    = lane >> 4;
  const int m    = lane & 15;
  const int blk  = blockIdx.x;
  const int l    = (blk & 7) * BLK_PER_IMG + (blk >> 3);
  const int p0   = l * 64;
  const int b    = p0 / HW;
  const short* xtb = xt + (size_t)b * HW * 128;

  const int spx   = lane;                   // pixel this thread stages
  const int p_s   = p0 + spx;
  const int choff = wv * 32;                // channel window staged (shorts)
  const int wsw   = spx & 3;                // write-side XOR key
  const int rsw   = m & 3;                  // read-side XOR key
  short* const myrow0 = &Ald[0][spx * AST];
  short* const myrow1 = &Ald[1][spx * AST];

  floatx4 acc[4][4];
  #pragma unroll
  for (int i = 0; i < 4; ++i)
    #pragma unroll
    for (int j = 0; j < 4; ++j) acc[i][j] = (floatx4){0.f, 0.f, 0.f, 0.f};

  // ---- stage tap 0 ----
  {
    float py = pmt[p_s];
    float px = pmt[(size_t)9 * NPIX + p_s];
    float mk = pmt[(size_t)18 * NPIX + p_s];
    Corner c = corner_setup(py, px, mk, xtb, choff);
    #pragma unroll
    for (int i = 0; i < 4; ++i) {
      short8 s00 = *(const short8*)(c.r00 + i * 8);
      short8 s01 = *(const short8*)(c.r01 + i * 8);
      short8 s10 = *(const short8*)(c.r10 + i * 8);
      short8 s11 = *(const short8*)(c.r11 + i * 8);
      *(short8*)(myrow0 + ((wv * 4 + i) ^ wsw) * 8) = interp8(s00, s01, s10, s11, c);
    }
  }
  // preload pmt for tap 1
  float pyN = pmt[(size_t)1 * NPIX + p_s];
  float pxN = pmt[(size_t)10 * NPIX + p_s];
  float mkN = pmt[(size_t)19 * NPIX + p_s];
  __syncthreads();

  for (int tap = 0; tap < 9; ++tap) {
    const short* bufr = Ald[tap & 1];
    short* const roww = (tap & 1) ? myrow0 : myrow1;
    const bool nxt = (tap < 8);

    Corner c;
    if (nxt) c = corner_setup(pyN, pxN, mkN, xtb, choff);
    if (tap < 7) {
      pyN = pmt[(size_t)(tap + 2) * NPIX + p_s];
      pxN = pmt[(size_t)(tap + 11) * NPIX + p_s];
      mkN = pmt[(size_t)(tap + 20) * NPIX + p_s];
    }

    short8 gp00, gp01, gp10, gp11;          // previous chunk's gathers
    #pragma unroll
    for (int kq = 0; kq < 4; ++kq) {
      // B-frags first (their waitcnt must not drain this kq's gathers)
      short8 bf[4];
      #pragma unroll
      for (int nl = 0; nl < 4; ++nl)
        bf[nl] = *(const short8*)(Bt2f + (size_t)((tap * 4 + kq) * 16 + wv * 4 + nl) * 512 + lane * 8);
      // next-tap gather, chunk kq
      short8 g00, g01, g10, g11;
      if (nxt) {
        g00 = *(const short8*)(c.r00 + kq * 8);
        g01 = *(const short8*)(c.r01 + kq * 8);
        g10 = *(const short8*)(c.r10 + kq * 8);
        g11 = *(const short8*)(c.r11 + kq * 8);
      }
      // A-frags from LDS + MFMAs
      short8 af[4];
      #pragma unroll
      for (int mt = 0; mt < 4; ++mt)
        af[mt] = *(const short8*)(bufr + (mt * 16 + m) * AST + ((kq * 4 + q) ^ rsw) * 8);
      #pragma unroll
      for (int mt = 0; mt < 4; ++mt)
        #pragma unroll
        for (int nl = 0; nl < 4; ++nl)
          acc[mt][nl] = __builtin_amdgcn_mfma_f32_16x16x32_bf16(af[mt], bf[nl], acc[mt][nl], 0, 0, 0);
      // interp + write PREVIOUS chunk (its gathers have had a full kq-step)
      if (nxt && kq > 0)
        *(short8*)(roww + ((wv * 4 + kq - 1) ^ wsw) * 8) = interp8(gp00, gp01, gp10, gp11, c);
      gp00 = g00; gp01 = g01; gp10 = g10; gp11 = g11;
    }
    if (nxt) {
      *(short8*)(roww + ((wv * 4 + 3) ^ wsw) * 8) = interp8(gp00, gp01, gp10, gp11, c);
      __syncthreads();
    }
  }

  // ---- epilogue: direct stores.  D: row=q*4+r -> px mt*16+q*4+r, col=m ----
  const int hw0 = p0 % HW;
  #pragma unroll
  for (int nl = 0; nl < 4; ++nl) {
    const int o = wv * 64 + nl * 16 + m;
    const float bs = bias[o];
    float* op = out + (size_t)(b * COUT + o) * HW + hw0;
    #pragma unroll
    for (int mt = 0; mt < 4; ++mt) {
      floatx4 v = acc[mt][nl];
      v[0] += bs; v[1] += bs; v[2] += bs; v[3] += bs;
      *(floatx4*)(op + mt * 16 + q * 4) = v;
    }
  }
}

// ---------------------------------------------------------------------------
extern "C" void kernel_launch(void* const* d_in, const int* in_sizes, int n_in,
                              void* d_out, int out_size, void* d_ws, size_t ws_size,
                              hipStream_t stream) {
  const float* x        = (const float*)d_in[0];
  const float* offset_w = (const float*)d_in[1];
  const float* offset_b = (const float*)d_in[2];
  const float* mask_w   = (const float*)d_in[3];
  const float* mask_b   = (const float*)d_in[4];
  const float* weight   = (const float*)d_in[5];
  const float* bias     = (const float*)d_in[6];
  float* out = (float*)d_out;

  char* ws = (char*)d_ws;
  const size_t XT_BYTES  = (size_t)NPIX * 128 * 2;        // 18,874,368
  const size_t PMT_BYTES = (size_t)27 * NPIX * 4;         //  7,962,624
  const size_t BT2_BYTES = (size_t)9 * 4 * 16 * 512 * 2;  //    589,824
  short* xtp  = (short*)ws;
  float* pmt  = (float*)(ws + XT_BYTES);
  short* Bt2f = (short*)(ws + XT_BYTES + PMT_BYTES);
  short* Bt1f = (short*)(ws + XT_BYTES + PMT_BYTES + BT2_BYTES);

  prep_weights<<<dim3(1296), dim3(256), 0, stream>>>(weight, offset_w, mask_w, Bt2f, Bt1f);
  transpose_x<<<dim3(NPIX / 64), dim3(256), 0, stream>>>(x, xtp);
  offmask_kernel<<<dim3(NPIX / 64), dim3(256), 0, stream>>>(xtp, Bt1f, offset_b, mask_b, pmt);
  deform_main<<<dim3(NPIX / 64), dim3(256), 0, stream>>>(xtp, Bt2f, pmt, bias, out);
}